// Round 10
// baseline (3212.745 us; speedup 1.0000x reference)
//
#include <hip/hip_runtime.h>
#include <math.h>

// FWI forward: 10 shots, 1000 steps, padded grid 130x160 (NBC=30).
// R10: 4 blocks per shot (z-split rows {33,33,32,32}) -> 40 CUs instead of 10.
// Per thread 3 rows x 4 cells: BOTH field generations AND both coefficient
// streams live in registers (~48 persistent); Ps (22KB, no z-halo) only for
// intra-block neighbor exchange. Cross-block halo: edge threads export their
// 2 new boundary rows as relaxed agent-scope u64 atomics (MALL-coherent,
// bypasses non-coherent per-XCD L2), barrier drains vmcnt, tid0/1 release-
// store a monotonic flag=t+1; importers acquire-poll flag>=t then atomic-load
// the 2 remote float4s they need (same-x vertical neighbors). Parity double-
// buffer (t&1) removes the WAR window; flag chain bounds skew<=1, deadlock-
// free (40 blocks co-resident). Flags+halo zeroed in setup1 each launch
// (graph-replay safe). Arithmetic bit-identical to R9 (absmax must stay .619).

#define SROW 168
#define PSZ (33 * SROW)          // rows 0..32, no z-halo; col = x + 4
#define DTf 0.0008f
#define C2f 1.3333333333333333f
#define C3f (-0.08333333333333333f)
#define HALO_OFF 172032          // byte offset in d_ws: 38,400 floats halo
#define FLAG_OFF 331776          // 60 u32 flags

#define LD4(arr, i) (*reinterpret_cast<const float4*>(&(arr)[i]))
#define LD2(arr, i) (*reinterpret_cast<const float2*>(&(arr)[i]))
#define ST4(arr, i, v) (*reinterpret_cast<float4*>(&(arr)[i]) = (v))

// ---------- setup 1: velmin, wavelet, amps + zero halo/flag buffers ----------
__global__ __launch_bounds__(1024) void fwi_setup1(const float* __restrict__ v,
                                                   float* __restrict__ ws,
                                                   float* __restrict__ halo,
                                                   unsigned int* __restrict__ flags) {
    int tid = threadIdx.x;
    for (int i = tid; i < 38400; i += 1024) halo[i] = 0.0f;
    if (tid < 60) flags[tid] = 0u;
    float m = 3.402823466e38f;
    for (int i = tid; i < 7000; i += 1024) m = fminf(m, v[i]);
    #pragma unroll
    for (int off = 32; off > 0; off >>= 1) m = fminf(m, __shfl_down(m, off, 64));
    __shared__ float red[16];
    if ((tid & 63) == 0) red[tid >> 6] = m;
    __syncthreads();
    if (tid == 0) {
        float mm = red[0];
        for (int i = 1; i < 16; ++i) mm = fminf(mm, red[i]);
        ws[1010] = mm * 1000.0f + 3000.0f;
    }
    if (tid < 1000) {
        float w = 0.0f;
        if (tid < 111) {
            float a = (float)(55 - tid) * 0.06283185307179587f;
            float b = a * a;
            w = (1.0f - 2.0f * b) * expf(-b);
        }
        ws[tid] = w;
    }
    if (tid >= 1000 && tid < 1010) {
        int l = tid - 1000;
        float vd = v[100 + 11 * l] * 1000.0f + 3000.0f;
        float bdt = vd * DTf;
        ws[tid] = bdt * bdt;
    }
}

// ---------- setup 2: per-cell constants AL (alpha), T1 (temp1) ----------
__global__ __launch_bounds__(256) void fwi_setup2(const float* __restrict__ v,
                                                  const float* __restrict__ ws,
                                                  float* __restrict__ AL,
                                                  float* __restrict__ T1) {
    int c = blockIdx.x * 256 + threadIdx.x;
    if (c >= 130 * 160) return;
    float velmin = ws[1010];
    int z = c / 160;
    int x = c - z * 160;
    int iz = min(max(z - 30, 0), 69);
    int ix = min(max(x - 30, 0), 99);
    float vd = v[iz * 100 + ix] * 1000.0f + 3000.0f;
    float tt = vd * DTf / 10.0f;
    float al = tt * tt;
    int qx = max(29 - x, x - 130);
    int qz = max(29 - z, z - 100);
    int q = (qx >= 0) ? qx : qz;
    float kdt = 0.0f;
    if (q >= 0) {
        float kap3 = 3.0f * velmin * 16.118095650958319f / 580.0f;
        float r = (float)q * (10.0f / 290.0f);
        kdt = kap3 * (r * r) * DTf;
    }
    AL[c] = al;
    T1[c] = 2.0f - 5.0f * al - kdt;    // temp2 = t1 + 5*al - 1 (R4-validated)
}

__device__ __forceinline__ float cellq(float l2, float l1, float cc, float r1, float r2,
                                       float u1, float u2, float d1, float d2,
                                       float al, float t1, float p0) {
    float lap = C2f * ((l1 + r1) + (u1 + d1)) + C3f * ((l2 + r2) + (u2 + d2));
    float t2  = t1 + 5.0f * al - 1.0f;
    return t1 * cc - t2 * p0 + al * lap;
}

__device__ __forceinline__ float4 ld_remote16(unsigned long long* p) {
    union { unsigned long long u; float2 f; } a, b;
    a.u = __hip_atomic_load(p,     __ATOMIC_RELAXED, __HIP_MEMORY_SCOPE_AGENT);
    b.u = __hip_atomic_load(p + 1, __ATOMIC_RELAXED, __HIP_MEMORY_SCOPE_AGENT);
    return make_float4(a.f.x, a.f.y, b.f.x, b.f.y);
}
__device__ __forceinline__ void st_remote16(unsigned long long* p, float4 v) {
    union { unsigned long long u; float2 f; } c;
    c.f = make_float2(v.x, v.y);
    __hip_atomic_store(p,     c.u, __ATOMIC_RELAXED, __HIP_MEMORY_SCOPE_AGENT);
    c.f = make_float2(v.z, v.w);
    __hip_atomic_store(p + 1, c.u, __ATOMIC_RELAXED, __HIP_MEMORY_SCOPE_AGENT);
}

// one row's 4-cell update; r is a literal
#define ROWQ(r, CUR, OLD, U1, U2, D1, D2) do {                                   \
    float2 hl = LD2(Ps, pcb + (r)*SROW - 2);                                     \
    float2 hr = LD2(Ps, pcb + (r)*SROW + 4);                                     \
    float4 c = (CUR)[r]; float4 p0 = (OLD)[r];                                   \
    float4 q;                                                                    \
    q.x = cellq(hl.x,hl.y,c.x,c.y,c.z,(U1).x,(U2).x,(D1).x,(D2).x,alr[r].x,t1r[r].x,p0.x); \
    q.y = cellq(hl.y,c.x,c.y,c.z,c.w,(U1).y,(U2).y,(D1).y,(D2).y,alr[r].y,t1r[r].y,p0.y);  \
    q.z = cellq(c.x,c.y,c.z,c.w,hr.x,(U1).z,(U2).z,(D1).z,(D2).z,alr[r].z,t1r[r].z,p0.z);  \
    q.w = cellq(c.y,c.z,c.w,hr.x,hr.y,(U1).w,(U2).w,(D1).w,(D2).w,alr[r].w,t1r[r].w,p0.w); \
    if (isrc && (r) == 1) {                                                      \
        q.x += (ls==0)?as:0.0f; q.y += (ls==1)?as:0.0f;                          \
        q.z += (ls==2)?as:0.0f; q.w += (ls==3)?as:0.0f; }                        \
    (OLD)[r] = q;                                                                \
} while (0)

#define STEP(CUR, OLD, T) do {                                                   \
    const int par = (T) & 1;                                                     \
    float4 RT1 = z4, RT2 = z4, RD1 = z4, RD2 = z4;                               \
    if (g == 0 && seg > 0) {                                                     \
        while (__hip_atomic_load(flags + (bnd3m*2 + 0), __ATOMIC_ACQUIRE,        \
                                 __HIP_MEMORY_SCOPE_AGENT) < (unsigned)(T)) {}   \
        unsigned long long* hb = halo_u + (size_t)(bnd3m*4 + (1 - par)*2 + 0)*160;\
        RT2 = ld_remote16(hb + qx*2);                                            \
        RT1 = ld_remote16(hb + 80 + qx*2);                                       \
    }                                                                            \
    if (g == 10 && seg < 3) {                                                    \
        while (__hip_atomic_load(flags + (bnd3*2 + 1), __ATOMIC_ACQUIRE,         \
                                 __HIP_MEMORY_SCOPE_AGENT) < (unsigned)(T)) {}   \
        unsigned long long* hb = halo_u + (size_t)(bnd3*4 + (1 - par)*2 + 1)*160;\
        RD1 = ld_remote16(hb + qx*2);                                            \
        RD2 = ld_remote16(hb + 80 + qx*2);                                       \
    }                                                                            \
    if (act) {                                                                   \
        const float as = ((T) < 111 && seg == 0) ? amp * Wv[(T)] : 0.0f;         \
        float4 tA1 = LD4(Ps, (g > 0) ? pcb - SROW   : pcb);                      \
        float4 tA2 = LD4(Ps, (g > 0) ? pcb - 2*SROW : pcb);                      \
        float4 tB1 = LD4(Ps, (g < 10) ? pcb + 3*SROW : pcb);                     \
        float4 tB2 = LD4(Ps, (g < 10) ? pcb + 4*SROW : pcb);                     \
        float4 AU1 = (g > 0)  ? tA1 : RT1;                                       \
        float4 AU2 = (g > 0)  ? tA2 : RT2;                                       \
        float4 BD1 = (g < 10) ? tB1 : RD1;                                       \
        float4 BD2 = (g < 10) ? tB2 : RD2;                                       \
        float4 d20 = vr2 ? (CUR)[2] : BD1;   /* d2 of row 0 */                   \
        float4 d11 = vr2 ? (CUR)[2] : BD1;   /* d1 of row 1 */                   \
        float4 d21 = vr2 ? BD1 : BD2;        /* d2 of row 1 */                   \
        if (g == 0) {                                                            \
            ROWQ(2, CUR, OLD, (CUR)[1], (CUR)[0], BD1, BD2);                     \
            ROWQ(0, CUR, OLD, AU1, AU2, (CUR)[1], d20);                          \
            ROWQ(1, CUR, OLD, (CUR)[0], AU1, d11, d21);                          \
        } else {                                                                 \
            ROWQ(0, CUR, OLD, AU1, AU2, (CUR)[1], d20);                          \
            ROWQ(1, CUR, OLD, (CUR)[0], AU1, d11, d21);                          \
            if (vr2) ROWQ(2, CUR, OLD, (CUR)[1], (CUR)[0], BD1, BD2);            \
        }                                                                        \
        if (g == 0 && seg > 0) {            /* export top rows 0,1 upward */     \
            unsigned long long* eb = halo_u + (size_t)(bnd3m*4 + par*2 + 1)*160; \
            st_remote16(eb + qx*2, (OLD)[0]);                                    \
            st_remote16(eb + 80 + qx*2, (OLD)[1]);                               \
        }                                                                        \
        if (g == 10 && seg < 3) {           /* export rows NR-2,NR-1 downward */ \
            unsigned long long* eb = halo_u + (size_t)(bnd3*4 + par*2 + 0)*160;  \
            float4 e0 = vr2 ? (OLD)[1] : (OLD)[0];                               \
            float4 e1 = vr2 ? (OLD)[2] : (OLD)[1];                               \
            st_remote16(eb + qx*2, e0);                                          \
            st_remote16(eb + 80 + qx*2, e1);                                     \
        }                                                                        \
    }                                                                            \
    __syncthreads();                         /* reads done + exports drained */  \
    if (tid == 0 && seg < 3)                                                     \
        __hip_atomic_store(flags + (bnd3*2 + 0), (unsigned)(T) + 1,              \
                           __ATOMIC_RELEASE, __HIP_MEMORY_SCOPE_AGENT);          \
    if (tid == 1 && seg > 0)                                                     \
        __hip_atomic_store(flags + (bnd3m*2 + 1), (unsigned)(T) + 1,             \
                           __ATOMIC_RELEASE, __HIP_MEMORY_SCOPE_AGENT);          \
    if (act) {                                                                   \
        ST4(Ps, pcb, (OLD)[0]);                                                  \
        ST4(Ps, pcb + SROW, (OLD)[1]);                                           \
        if (vr2) ST4(Ps, pcb + 2*SROW, (OLD)[2]);                                \
    }                                                                            \
    __syncthreads();                         /* commits visible */               \
    if (seg == 0 && tid < 100)                                                   \
        out[outb + (T)*100 + tid] = Ps[31*SROW + 34 + tid];                      \
} while (0)

// ---------- main: 40 blocks = 10 shots x 4 z-segments ----------
__global__ __launch_bounds__(512) void fwi_main(const float4* __restrict__ AL4,
                                                const float4* __restrict__ T14,
                                                const float* __restrict__ ws,
                                                float* __restrict__ halo,
                                                unsigned int* __restrict__ flags,
                                                float* __restrict__ out) {
    __shared__ float Ps[PSZ];
    __shared__ float Wv[128];
    const int tid = threadIdx.x;
    const int bid = blockIdx.x;
    const int shot = bid >> 2, seg = bid & 3;
    const int Z0 = seg * 33 - ((seg >= 3) ? 1 : 0);   // 0,33,66,98
    const int NR = (seg < 2) ? 33 : 32;
    unsigned long long* halo_u = (unsigned long long*)halo;
    const int bnd3  = shot * 3 + seg;        // valid when seg<3
    const int bnd3m = shot * 3 + seg - 1;    // valid when seg>0
    const int outb = shot * 100000;

    for (int i = tid; i < PSZ; i += 512) Ps[i] = 0.0f;
    if (tid < 128) Wv[tid] = (tid < 111) ? ws[tid] : 0.0f;

    const int g  = tid / 40;                 // z-group 0..10 active
    const int qx = tid - g * 40;
    const bool act = (g <= 10);
    const bool vr2 = act && (3 * g + 2 < NR);    // row r=2 valid (false: g10,seg>=2)
    const float amp = ws[1000 + shot];
    const int xs = 30 + 11 * shot;
    const bool isrc = (seg == 0) && (g == 10) && (qx == (xs >> 2));  // z=31 = g10,r1
    const int ls = xs & 3;
    const int pcb = 3 * g * SROW + 4 * qx + 4;
    const float4 z4 = make_float4(0.f, 0.f, 0.f, 0.f);

    // hoist coefficients into registers (per-thread, time-invariant)
    float4 alr[3], t1r[3];
    #pragma unroll
    for (int r = 0; r < 3; ++r) {
        alr[r] = z4; t1r[r] = z4;
        if (act && (3 * g + r < NR)) {
            int cq = (Z0 + 3 * g + r) * 40 + qx;
            alr[r] = AL4[cq]; t1r[r] = T14[cq];
        }
    }
    float4 pA[3], pB[3];
    #pragma unroll
    for (int r = 0; r < 3; ++r) { pA[r] = z4; pB[r] = z4; }
    __syncthreads();

    for (int t = 0; t < 1000; t += 2) {
        STEP(pB, pA, t);        // p1=pB, p0=pA -> new field lands in pA
        STEP(pA, pB, t + 1);
    }
}

extern "C" void kernel_launch(void* const* d_in, const int* in_sizes, int n_in,
                              void* d_out, int out_size, void* d_ws, size_t ws_size,
                              hipStream_t stream) {
    const float* v = (const float*)d_in[0];
    float* ws = (float*)d_ws;
    float* AL = (float*)((char*)d_ws + 4096);
    float* T1 = (float*)((char*)d_ws + 4096 + 83200);
    float* halo = (float*)((char*)d_ws + HALO_OFF);
    unsigned int* flags = (unsigned int*)((char*)d_ws + FLAG_OFF);
    float* out = (float*)d_out;

    fwi_setup1<<<1, 1024, 0, stream>>>(v, ws, halo, flags);
    fwi_setup2<<<82, 256, 0, stream>>>(v, ws, AL, T1);
    fwi_main<<<40, 512, 0, stream>>>((const float4*)AL, (const float4*)T1,
                                     ws, halo, flags, out);
}

// Round 11
// 3135.450 us; speedup vs baseline: 1.0247x; 1.0247x over previous
//
#include <hip/hip_runtime.h>
#include <math.h>

// FWI forward: 10 shots, 1000 steps, padded grid 130x160 (NBC=30).
// R11 = R9 (proven: 3.09ms, zero spill, absmax .619) + two targeted changes.
// R10's 40-block halo experiment showed agent-scope sync costs ~2.5us/step ->
// abandoned. R9's counters decompose to VALU 4370 + LDS 2450 + barriers 600
// = 7420 cy/step measured, i.e. ~ZERO LDS/VALU overlap (waves in barrier
// lockstep read-then-compute simultaneously). Changes:
//  1. software-stagger: row r+1's LDS operands (hl/hr, p0) are loaded into
//     parity-named regs BEFORE row r's compute -> LDS hides under VALU.
//  2. T2 precomputed as a 3rd coefficient stream (R6-validated bit-exact);
//     removes fma+add per cell from the inner loop.
// Everything else identical to R9: q-lag in-place update, p0 rows 0..6 in
// per-thread LDS stride 28 (conflict-free), rows 7..10 in regs, 2-row coef
// capture-then-prefetch, zlim = min(130-z0, RH).

#define SROW 168                 // Ps row stride; col = x + 4
#define PSZ (136 * SROW)         // stored rows -2..133
#define RH 11                    // rows per thread
#define DTf 0.0008f
#define C2f 1.3333333333333333f  // 4/3
#define C3f (-0.08333333333333333f) // -1/12

#define LD4(arr, i) (*reinterpret_cast<const float4*>(&(arr)[i]))
#define LD2(arr, i) (*reinterpret_cast<const float2*>(&(arr)[i]))
#define ST4(arr, i, v) (*reinterpret_cast<float4*>(&(arr)[i]) = (v))

// ---------- setup 1: velmin reduction, Ricker wavelet, source amplitudes ----------
__global__ __launch_bounds__(1024) void fwi_setup1(const float* __restrict__ v,
                                                   float* __restrict__ ws) {
    int tid = threadIdx.x;
    float m = 3.402823466e38f;
    for (int i = tid; i < 7000; i += 1024) m = fminf(m, v[i]);
    #pragma unroll
    for (int off = 32; off > 0; off >>= 1) m = fminf(m, __shfl_down(m, off, 64));
    __shared__ float red[16];
    if ((tid & 63) == 0) red[tid >> 6] = m;
    __syncthreads();
    if (tid == 0) {
        float mm = red[0];
        for (int i = 1; i < 16; ++i) mm = fminf(mm, red[i]);
        ws[1010] = mm * 1000.0f + 3000.0f;   // denormalized velmin
    }
    // Ricker wavelet: nw=111, nc=55, f*dt*pi = 0.06283185307179587
    if (tid < 1000) {
        float w = 0.0f;
        if (tid < 111) {
            float a = (float)(55 - tid) * 0.06283185307179587f;
            float b = a * a;
            w = (1.0f - 2.0f * b) * expf(-b);
        }
        ws[tid] = w;
    }
    // src_amp[l] = ((v[1][11l]*1000+3000)*DT)^2
    if (tid >= 1000 && tid < 1010) {
        int l = tid - 1000;
        float vd = v[100 + 11 * l] * 1000.0f + 3000.0f;
        float bdt = vd * DTf;
        ws[tid] = bdt * bdt;
    }
}

// ---------- setup 2: per-cell constants AL, T1, T2; 132-row padded ----------
__global__ __launch_bounds__(256) void fwi_setup2(const float* __restrict__ v,
                                                  const float* __restrict__ ws,
                                                  float* __restrict__ AL,
                                                  float* __restrict__ T1,
                                                  float* __restrict__ T2) {
    int c = blockIdx.x * 256 + threadIdx.x;
    if (c >= 132 * 160) return;
    if (c >= 130 * 160) { AL[c] = 0.0f; T1[c] = 0.0f; T2[c] = 0.0f; return; }
    float velmin = ws[1010];
    int z = c / 160;
    int x = c - z * 160;
    int iz = min(max(z - 30, 0), 69);
    int ix = min(max(x - 30, 0), 99);
    float vd = v[iz * 100 + ix] * 1000.0f + 3000.0f;
    float tt = vd * DTf / 10.0f;       // v*DT/DX
    float al = tt * tt;                // alpha
    int qx = max(29 - x, x - 130);
    int qz = max(29 - z, z - 100);
    int q = (qx >= 0) ? qx : qz;
    float kdt = 0.0f;
    if (q >= 0) {
        float kap3 = 3.0f * velmin * 16.118095650958319f / 580.0f; // 3*velmin*ln(1e7)/(2*290)
        float r = (float)q * (10.0f / 290.0f);
        kdt = kap3 * (r * r) * DTf;
    }
    AL[c] = al;
    T1[c] = 2.0f - 5.0f * al - kdt;    // temp1
    T2[c] = 1.0f - kdt;                // temp2 (R6-validated bit-exact path)
}

__device__ __forceinline__ float cellq(float l2, float l1, float cc, float r1, float r2,
                                       float u1, float u2, float d1, float d2,
                                       float al, float t1, float t2, float p0) {
    float lap = C2f * ((l1 + r1) + (u1 + d1)) + C3f * ((l2 + r2) + (u2 + d2));
    return t1 * cc - t2 * p0 + al * lap;
}

// ---------- main: one block per shot, 1000 steps ----------
__global__ __launch_bounds__(512) void fwi_main(const float4* __restrict__ AL4,
                                                const float4* __restrict__ T14,
                                                const float4* __restrict__ T24,
                                                const float* __restrict__ ws,
                                                float* __restrict__ out) {
    __shared__ float Ps[PSZ];          // p1 mirror, haloed (91,392 B)
    __shared__ float P0s[512 * 28];    // p0 rows 0..6, per-thread stride 28 (57,344 B)
    __shared__ float Wv[128];          // Ricker wavelet (nonzero only t < 111)
    const int tid = threadIdx.x;
    const int shot = blockIdx.x;

    for (int i = tid; i < PSZ; i += 512) Ps[i] = 0.0f;
    for (int i = tid; i < 512 * 28; i += 512) P0s[i] = 0.0f;
    if (tid < 128) Wv[tid] = (tid < 111) ? ws[tid] : 0.0f;

    const int g  = tid / 40;            // z-group 0..11 active, >=12 idle
    const int qx = tid - g * 40;        // x-quad 0..39, cells x0 = 4*qx
    const int z0 = g * RH;
    const bool act = (g < 12);
    const float amp = ws[1000 + shot];
    const int xs = 30 + 11 * shot;      // source x (z=31 -> g=2, r=9)
    const bool isrc = act && (g == 2) && (qx == (xs >> 2));
    const int ls = xs & 3;
    const int pc0 = (z0 + 2) * SROW + 4 * qx + 4;  // Ps index of row z0 quad
    const int cb0 = z0 * 40 + qx;                  // coefficient quad index
    const int p0b = tid * 28;                      // P0s per-thread base (words)
    const int zlim = min(130 - z0, RH);            // g<11: 11, g==11: 9

    float4 pA[RH];                      // p1, morphs into p_new via q-lag
    float4 p0r[4];                      // p0 rows 7..10
    #pragma unroll
    for (int r = 0; r < RH; ++r) pA[r] = make_float4(0.f, 0.f, 0.f, 0.f);
    #pragma unroll
    for (int r = 0; r < 4; ++r) p0r[r] = make_float4(0.f, 0.f, 0.f, 0.f);
    __syncthreads();

    for (int t = 0; t < 1000; ++t) {
        const float as = (t < 111) ? amp * Wv[t] : 0.0f;

        // ---- phase A: in-place stencil, q-lag + parity software prefetch ----
        if (act) {
            // rolling coefficients (3 streams), 2-row lead
            float4 ae = AL4[cb0],      te  = T14[cb0],      se  = T24[cb0];
            float4 ao = AL4[cb0 + 40], to_ = T14[cb0 + 40], so_ = T24[cb0 + 40];
            float4 hu2 = LD4(Ps, pc0 - 2 * SROW);
            float4 hu1 = LD4(Ps, pc0 - 1 * SROW);
            float4 hd1 = make_float4(0.f, 0.f, 0.f, 0.f);
            float4 hd2 = make_float4(0.f, 0.f, 0.f, 0.f);
            float4 qm2 = make_float4(0.f, 0.f, 0.f, 0.f);
            float4 qm1 = make_float4(0.f, 0.f, 0.f, 0.f);
            // 1-row-lead LDS prefetch (parity regs)
            float2 hle = LD2(Ps, pc0 - 2), hlo = make_float2(0.f, 0.f);
            float2 hre = LD2(Ps, pc0 + 4), hro = make_float2(0.f, 0.f);
            float4 p0e = LD4(P0s, p0b),    p0o = make_float4(0.f, 0.f, 0.f, 0.f);
            #pragma unroll
            for (int r = 0; r < RH; ++r) {
                if (r < zlim) {
                    // capture THIS row's operands from parity slots
                    float4 al = (r & 1) ? ao : ae;
                    float4 t1 = (r & 1) ? to_ : te;
                    float4 t2 = (r & 1) ? so_ : se;
                    float2 hl = (r & 1) ? hlo : hle;
                    float2 hr = (r & 1) ? hro : hre;
                    float4 p0 = (r < 7) ? ((r & 1) ? p0o : p0e)
                                        : p0r[(r >= 7) ? r - 7 : 0];
                    // prefetch row r+1 LDS operands into opposite parity
                    if (r < RH - 1) {
                        const int pcn = pc0 + (r + 1) * SROW;
                        if (r & 1) { hle = LD2(Ps, pcn - 2); hre = LD2(Ps, pcn + 4); }
                        else       { hlo = LD2(Ps, pcn - 2); hro = LD2(Ps, pcn + 4); }
                        if (r < 6) {     // p0 rows 1..6 come from LDS
                            if (r & 1) p0e = LD4(P0s, p0b + 4 * (r + 1));
                            else       p0o = LD4(P0s, p0b + 4 * (r + 1));
                        }
                    }
                    // prefetch coefs for row r+2 into same-parity slot
                    if (r < RH - 2) {
                        if (r & 1) { ao = AL4[cb0 + (r + 2) * 40];
                                     to_ = T14[cb0 + (r + 2) * 40];
                                     so_ = T24[cb0 + (r + 2) * 40]; }
                        else       { ae = AL4[cb0 + (r + 2) * 40];
                                     te = T14[cb0 + (r + 2) * 40];
                                     se = T24[cb0 + (r + 2) * 40]; }
                    }
                    if (r == 8) {                       // z-halo below, 1-row lead
                        hd1 = LD4(Ps, pc0 + RH * SROW);
                        hd2 = LD4(Ps, pc0 + (RH + 1) * SROW);
                    }
                    float4 c  = pA[r];
                    float4 u1 = (r == 0) ? hu1 : pA[(r >= 1) ? r - 1 : 0];
                    float4 u2 = (r == 0) ? hu2 :
                                ((r == 1) ? hu1 : pA[(r >= 2) ? r - 2 : 0]);
                    float4 d1 = (r == RH - 1) ? hd1 : pA[(r + 1 < RH) ? r + 1 : 0];
                    float4 d2 = (r == RH - 1) ? hd2 :
                                ((r == RH - 2) ? hd1 : pA[(r + 2 < RH) ? r + 2 : 0]);
                    float4 q;
                    q.x = cellq(hl.x, hl.y, c.x, c.y, c.z,
                                u1.x, u2.x, d1.x, d2.x, al.x, t1.x, t2.x, p0.x);
                    q.y = cellq(hl.y, c.x, c.y, c.z, c.w,
                                u1.y, u2.y, d1.y, d2.y, al.y, t1.y, t2.y, p0.y);
                    q.z = cellq(c.x, c.y, c.z, c.w, hr.x,
                                u1.z, u2.z, d1.z, d2.z, al.z, t1.z, t2.z, p0.z);
                    q.w = cellq(c.y, c.z, c.w, hr.x, hr.y,
                                u1.w, u2.w, d1.w, d2.w, al.w, t1.w, t2.w, p0.w);
                    if (r == 9 && isrc) {               // source injection (z=31)
                        q.x += (ls == 0) ? as : 0.0f;
                        q.y += (ls == 1) ? as : 0.0f;
                        q.z += (ls == 2) ? as : 0.0f;
                        q.w += (ls == 3) ? as : 0.0f;
                    }
                    // p0 <- old p1 center (owner-private)
                    if (r < 7) ST4(P0s, p0b + 4 * r, c);
                    else       p0r[(r >= 7) ? r - 7 : 0] = c;
                    // q-lag commit: rows r-1, r have consumed old pA[r-2]
                    if (r >= 2) pA[(r >= 2) ? r - 2 : 0] = qm2;
                    qm2 = qm1;
                    qm1 = q;
                }
            }
            // tail: commit the last two rows
            if (zlim == 11) { pA[9] = qm2; pA[10] = qm1; }
            else            { pA[7] = qm2; pA[8] = qm1; }   // g == 11 (zlim 9)
        }
        __syncthreads();               // all Ps reads complete

        // ---- phase B: commit p_new (now in pA) to Ps ----
        if (act) {
            #pragma unroll
            for (int r = 0; r < RH; ++r)
                if (r < zlim) ST4(Ps, pc0 + r * SROW, pA[r]);
        }
        __syncthreads();               // new p1 visible

        // ---- phase C: receivers z=31, x=30..129 ----
        if (tid < 100) out[shot * 100000 + t * 100 + tid] = Ps[33 * SROW + 34 + tid];
    }
}

extern "C" void kernel_launch(void* const* d_in, const int* in_sizes, int n_in,
                              void* d_out, int out_size, void* d_ws, size_t ws_size,
                              hipStream_t stream) {
    const float* v = (const float*)d_in[0];
    float* ws = (float*)d_ws;                           // [0..999] wavelet, [1000..1009] amps, [1010] velmin
    float* AL = (float*)((char*)d_ws + 4096);           // 21120 floats (132 rows)
    float* T1 = (float*)((char*)d_ws + 4096 + 84480);   // 21120 floats
    float* T2 = (float*)((char*)d_ws + 4096 + 168960);  // 21120 floats
    float* out = (float*)d_out;

    fwi_setup1<<<1, 1024, 0, stream>>>(v, ws);
    fwi_setup2<<<83, 256, 0, stream>>>(v, ws, AL, T1, T2);
    fwi_main<<<10, 512, 0, stream>>>((const float4*)AL, (const float4*)T1,
                                     (const float4*)T2, ws, out);
}

// Round 12
// 2589.194 us; speedup vs baseline: 1.2408x; 1.2110x over previous
//
#include <hip/hip_runtime.h>
#include <math.h>

// FWI forward: 10 shots, 1000 steps, padded grid 130x160 (NBC=30).
// R12: LDS-traffic diet. R11 showed LDS pipe (~4,240cy/CU-step) and VALU
// (~4,200cy) both ~56% busy, dependency-stalled -> cut LDS traffic:
//  - p0 rows 2..10 in registers (36 VGPR), rows 0..1 in P0g[24][168]
//    (grid layout, lane-stride 4 words = conflict-free b128, 16KB).
//  - receivers stored straight from q registers (phase C removed).
//  - cellq on float2 ext-vectors (elementwise, bit-identical ops) to let
//    the backend emit v_pk_*_f32 packed math.
// LDS b128/thread-step 29 -> 19. Total LDS 108KB. q-lag + zlim as R9.

#define SROW 168                 // Ps row stride; col = x + 4
#define PSZ (136 * SROW)         // stored rows -2..133
#define P0G (24 * SROW)          // p0 rows 0,1 of each of 12 groups
#define RH 11                    // rows per thread
#define DTf 0.0008f
#define C2f 1.3333333333333333f  // 4/3
#define C3f (-0.08333333333333333f) // -1/12

typedef __attribute__((ext_vector_type(2))) float f2;

#define LD4(arr, i) (*reinterpret_cast<const float4*>(&(arr)[i]))
#define LDF2(arr, i) (*reinterpret_cast<const f2*>(&(arr)[i]))
#define ST4(arr, i, v) (*reinterpret_cast<float4*>(&(arr)[i]) = (v))

// ---------- setup 1: velmin reduction, Ricker wavelet, source amplitudes ----------
__global__ __launch_bounds__(1024) void fwi_setup1(const float* __restrict__ v,
                                                   float* __restrict__ ws) {
    int tid = threadIdx.x;
    float m = 3.402823466e38f;
    for (int i = tid; i < 7000; i += 1024) m = fminf(m, v[i]);
    #pragma unroll
    for (int off = 32; off > 0; off >>= 1) m = fminf(m, __shfl_down(m, off, 64));
    __shared__ float red[16];
    if ((tid & 63) == 0) red[tid >> 6] = m;
    __syncthreads();
    if (tid == 0) {
        float mm = red[0];
        for (int i = 1; i < 16; ++i) mm = fminf(mm, red[i]);
        ws[1010] = mm * 1000.0f + 3000.0f;   // denormalized velmin
    }
    // Ricker wavelet: nw=111, nc=55, f*dt*pi = 0.06283185307179587
    if (tid < 1000) {
        float w = 0.0f;
        if (tid < 111) {
            float a = (float)(55 - tid) * 0.06283185307179587f;
            float b = a * a;
            w = (1.0f - 2.0f * b) * expf(-b);
        }
        ws[tid] = w;
    }
    // src_amp[l] = ((v[1][11l]*1000+3000)*DT)^2
    if (tid >= 1000 && tid < 1010) {
        int l = tid - 1000;
        float vd = v[100 + 11 * l] * 1000.0f + 3000.0f;
        float bdt = vd * DTf;
        ws[tid] = bdt * bdt;
    }
}

// ---------- setup 2: per-cell constants AL, T1, T2; 132-row padded ----------
__global__ __launch_bounds__(256) void fwi_setup2(const float* __restrict__ v,
                                                  const float* __restrict__ ws,
                                                  float* __restrict__ AL,
                                                  float* __restrict__ T1,
                                                  float* __restrict__ T2) {
    int c = blockIdx.x * 256 + threadIdx.x;
    if (c >= 132 * 160) return;
    if (c >= 130 * 160) { AL[c] = 0.0f; T1[c] = 0.0f; T2[c] = 0.0f; return; }
    float velmin = ws[1010];
    int z = c / 160;
    int x = c - z * 160;
    int iz = min(max(z - 30, 0), 69);
    int ix = min(max(x - 30, 0), 99);
    float vd = v[iz * 100 + ix] * 1000.0f + 3000.0f;
    float tt = vd * DTf / 10.0f;       // v*DT/DX
    float al = tt * tt;                // alpha
    int qx = max(29 - x, x - 130);
    int qz = max(29 - z, z - 100);
    int q = (qx >= 0) ? qx : qz;
    float kdt = 0.0f;
    if (q >= 0) {
        float kap3 = 3.0f * velmin * 16.118095650958319f / 580.0f; // 3*velmin*ln(1e7)/(2*290)
        float r = (float)q * (10.0f / 290.0f);
        kdt = kap3 * (r * r) * DTf;
    }
    AL[c] = al;
    T1[c] = 2.0f - 5.0f * al - kdt;    // temp1
    T2[c] = 1.0f - kdt;                // temp2 (R6/R11-validated)
}

static __device__ __forceinline__ f2 mkf2(float a, float b) { f2 r; r.x = a; r.y = b; return r; }

static __device__ __forceinline__ f2 cellq2(f2 l2, f2 l1, f2 cc, f2 r1, f2 r2,
                                            f2 u1, f2 u2, f2 d1, f2 d2,
                                            f2 al, f2 t1, f2 t2, f2 p0) {
    f2 lap = C2f * ((l1 + r1) + (u1 + d1)) + C3f * ((l2 + r2) + (u2 + d2));
    return t1 * cc - t2 * p0 + al * lap;
}

// ---------- main: one block per shot, 1000 steps ----------
__global__ __launch_bounds__(512) void fwi_main(const float4* __restrict__ AL4,
                                                const float4* __restrict__ T14,
                                                const float4* __restrict__ T24,
                                                const float* __restrict__ ws,
                                                float* __restrict__ out) {
    __shared__ float Ps[PSZ];      // p1 mirror, haloed (91,392 B)
    __shared__ float P0g[P0G];     // p0 rows 0,1 per group, grid layout (16,128 B)
    __shared__ float Wv[128];      // Ricker wavelet (nonzero only t < 111)
    const int tid = threadIdx.x;
    const int shot = blockIdx.x;

    for (int i = tid; i < PSZ; i += 512) Ps[i] = 0.0f;
    for (int i = tid; i < P0G; i += 512) P0g[i] = 0.0f;
    if (tid < 128) Wv[tid] = (tid < 111) ? ws[tid] : 0.0f;

    const int g  = tid / 40;            // z-group 0..11 active, >=12 idle
    const int qx = tid - g * 40;        // x-quad 0..39, cells x0 = 4*qx
    const int z0 = g * RH;
    const bool act = (g < 12);
    const float amp = ws[1000 + shot];
    const int xs = 30 + 11 * shot;      // source x (z=31 -> g=2, r=9)
    const bool isrc = act && (g == 2) && (qx == (xs >> 2));
    const int ls = xs & 3;
    const int pc0 = (z0 + 2) * SROW + 4 * qx + 4;  // Ps index of row z0 quad
    const int cb0 = z0 * 40 + qx;                  // coefficient quad index
    const int p0g0 = (g * 2) * SROW + 4 * qx;      // P0g index of row 0 quad
    const int zlim = min(130 - z0, RH);            // g<11: 11, g==11: 9
    const bool grec = act && (g == 2);             // this thread's r==9 is z=31
    const int xr0 = 4 * qx - 30;                   // receiver index of lane j=0

    float4 pA[RH];                      // p1, morphs into p_new via q-lag
    float4 p0r[9];                      // p0 rows 2..10
    #pragma unroll
    for (int r = 0; r < RH; ++r) pA[r] = make_float4(0.f, 0.f, 0.f, 0.f);
    #pragma unroll
    for (int r = 0; r < 9; ++r) p0r[r] = make_float4(0.f, 0.f, 0.f, 0.f);
    __syncthreads();

    for (int t = 0; t < 1000; ++t) {
        const float as = (t < 111) ? amp * Wv[t] : 0.0f;

        // ---- phase A: in-place stencil with 2-row q-lag ----
        if (act) {
            float4 hu2 = LD4(Ps, pc0 - 2 * SROW);
            float4 hu1 = LD4(Ps, pc0 - 1 * SROW);
            float4 hd1 = make_float4(0.f, 0.f, 0.f, 0.f);
            float4 hd2 = make_float4(0.f, 0.f, 0.f, 0.f);
            float4 qm2 = make_float4(0.f, 0.f, 0.f, 0.f);
            float4 qm1 = make_float4(0.f, 0.f, 0.f, 0.f);
            #pragma unroll
            for (int r = 0; r < RH; ++r) {
                if (r < zlim) {
                    if (r == 8) {                       // z-halo below, 1-row lead
                        hd1 = LD4(Ps, pc0 + RH * SROW);
                        hd2 = LD4(Ps, pc0 + (RH + 1) * SROW);
                    }
                    const int pc = pc0 + r * SROW;
                    f2 hl = LDF2(Ps, pc - 2);
                    f2 hr = LDF2(Ps, pc + 4);
                    float4 al4 = AL4[cb0 + r * 40];
                    float4 t14 = T14[cb0 + r * 40];
                    float4 t24 = T24[cb0 + r * 40];
                    float4 c  = pA[r];
                    float4 u1 = (r == 0) ? hu1 : pA[(r >= 1) ? r - 1 : 0];
                    float4 u2 = (r == 0) ? hu2 :
                                ((r == 1) ? hu1 : pA[(r >= 2) ? r - 2 : 0]);
                    float4 d1 = (r == RH - 1) ? hd1 : pA[(r + 1 < RH) ? r + 1 : 0];
                    float4 d2 = (r == RH - 1) ? hd2 :
                                ((r == RH - 2) ? hd1 : pA[(r + 2 < RH) ? r + 2 : 0]);
                    float4 p0 = (r < 2) ? LD4(P0g, p0g0 + r * SROW)
                                        : p0r[(r >= 2) ? r - 2 : 0];
                    // lo pair: cells x0, x0+1
                    f2 qlo = cellq2(hl, mkf2(hl.y, c.x), mkf2(c.x, c.y),
                                    mkf2(c.y, c.z), mkf2(c.z, c.w),
                                    mkf2(u1.x, u1.y), mkf2(u2.x, u2.y),
                                    mkf2(d1.x, d1.y), mkf2(d2.x, d2.y),
                                    mkf2(al4.x, al4.y), mkf2(t14.x, t14.y),
                                    mkf2(t24.x, t24.y), mkf2(p0.x, p0.y));
                    // hi pair: cells x0+2, x0+3
                    f2 qhi = cellq2(mkf2(c.x, c.y), mkf2(c.y, c.z), mkf2(c.z, c.w),
                                    mkf2(c.w, hr.x), hr,
                                    mkf2(u1.z, u1.w), mkf2(u2.z, u2.w),
                                    mkf2(d1.z, d1.w), mkf2(d2.z, d2.w),
                                    mkf2(al4.z, al4.w), mkf2(t14.z, t14.w),
                                    mkf2(t24.z, t24.w), mkf2(p0.z, p0.w));
                    float4 q = make_float4(qlo.x, qlo.y, qhi.x, qhi.y);
                    if (r == 9 && isrc) {               // source injection (z=31)
                        q.x += (ls == 0) ? as : 0.0f;
                        q.y += (ls == 1) ? as : 0.0f;
                        q.z += (ls == 2) ? as : 0.0f;
                        q.w += (ls == 3) ? as : 0.0f;
                    }
                    if (r == 9 && grec) {               // receivers z=31, x=30..129
                        const int ob = shot * 100000 + t * 100 + xr0;
                        if (xr0 >= 0   && xr0 <= 99)  out[ob]     = q.x;
                        if (xr0 >= -1  && xr0 <= 98)  out[ob + 1] = q.y;
                        if (xr0 >= -2  && xr0 <= 97)  out[ob + 2] = q.z;
                        if (xr0 >= -3  && xr0 <= 96)  out[ob + 3] = q.w;
                    }
                    // p0 <- old p1 center (owner-private)
                    if (r < 2) ST4(P0g, p0g0 + r * SROW, c);
                    else       p0r[(r >= 2) ? r - 2 : 0] = c;
                    // q-lag commit: rows r-1, r have consumed old pA[r-2]
                    if (r >= 2) pA[(r >= 2) ? r - 2 : 0] = qm2;
                    qm2 = qm1;
                    qm1 = q;
                }
            }
            // tail: commit the last two rows
            if (zlim == 11) { pA[9] = qm2; pA[10] = qm1; }
            else            { pA[7] = qm2; pA[8] = qm1; }   // g == 11 (zlim 9)
        }
        __syncthreads();               // all Ps reads complete

        // ---- phase B: commit p_new (now in pA) to Ps ----
        if (act) {
            #pragma unroll
            for (int r = 0; r < RH; ++r)
                if (r < zlim) ST4(Ps, pc0 + r * SROW, pA[r]);
        }
        __syncthreads();               // new p1 visible for next step
    }
}

extern "C" void kernel_launch(void* const* d_in, const int* in_sizes, int n_in,
                              void* d_out, int out_size, void* d_ws, size_t ws_size,
                              hipStream_t stream) {
    const float* v = (const float*)d_in[0];
    float* ws = (float*)d_ws;                           // [0..999] wavelet, [1000..1009] amps, [1010] velmin
    float* AL = (float*)((char*)d_ws + 4096);           // 21120 floats (132 rows)
    float* T1 = (float*)((char*)d_ws + 4096 + 84480);   // 21120 floats
    float* T2 = (float*)((char*)d_ws + 4096 + 168960);  // 21120 floats
    float* out = (float*)d_out;

    fwi_setup1<<<1, 1024, 0, stream>>>(v, ws);
    fwi_setup2<<<83, 256, 0, stream>>>(v, ws, AL, T1, T2);
    fwi_main<<<10, 512, 0, stream>>>((const float4*)AL, (const float4*)T1,
                                     (const float4*)T2, ws, out);
}